// Round 8
// baseline (211.329 us; speedup 1.0000x reference)
//
#include <hip/hip_runtime.h>
#include <math.h>

#define NRAYS 8192
#define RPB 8              // rays (= waves) per block
#define AS 136             // Ah row stride in f16 elems (pad vs 128 to spread banks)

typedef _Float16 half8 __attribute__((ext_vector_type(8)));
typedef _Float16 half2v __attribute__((ext_vector_type(2)));
typedef float floatx4 __attribute__((ext_vector_type(4)));

__device__ __forceinline__ float sigm(float x){ return 1.0f/(1.0f + __expf(-x)); }

// wave-local LDS sync: drain this wave's DS ops; no cross-wave barrier.
__device__ __forceinline__ void wsync(){
  __builtin_amdgcn_wave_barrier();
  __builtin_amdgcn_s_waitcnt(0xc07f);   // lgkmcnt(0) only
  __builtin_amdgcn_wave_barrier();
}

__launch_bounds__(512, 4)
__global__ void neus_render_kernel(
    const float* __restrict__ rays_o, const float* __restrict__ rays_d,
    const float* __restrict__ W1, const float* __restrict__ b1,
    const float* __restrict__ W2, const float* __restrict__ b2,
    const float* __restrict__ W3, const float* __restrict__ b3,
    const float* __restrict__ R1, const float* __restrict__ r1,
    const float* __restrict__ R2, const float* __restrict__ r2,
    const float* __restrict__ s_val, float* __restrict__ out)
{
  // ---- shared: weights (block-shared) + per-ray scratch. Total = 80 KB exactly.
  __shared__ __align__(16) _Float16 W2f[2048*8];     // 32 KB: 32 B-frags x 64 lanes x 8
  __shared__ __align__(16) _Float16 R2f[256*8];      // 4 KB
  __shared__ __align__(16) _Float16 Ah[RPB][16*AS];  // 34 KB: per-ray A staging
  __shared__ __align__(16) float sDm[RPB][128];      // 4 KB
  __shared__ __align__(16) float sSm[RPB][128];      // 4 KB
  __shared__ __align__(16) float fDs[RPB][16];       // 512 B
  __shared__ __align__(16) float fSs[RPB][16];       // 512 B
  __shared__ float b2f[128], w3f[128];               // 1 KB

  const int t = threadIdx.x;

  // ---- cooperative weight staging (only cross-wave cooperation in the kernel)
  #pragma unroll
  for (int r=0;r<4;r++){
    int row = t + r*512;                 // 0..2047: frag-major rows
    int i = row>>8, kt=(row>>6)&3, lr=row&63;
    int q = lr>>4, n = i*16 + (lr&15);
    half8 v;
    #pragma unroll
    for (int j=0;j<8;j++) v[j] = (_Float16)W2[(kt*32+q*8+j)*128 + n];
    *(half8*)&W2f[row*8] = v;
  }
  if (t < 256){
    int kt=t>>6, lr=t&63, q=lr>>4, col=lr&15;
    half8 v;
    #pragma unroll
    for (int j=0;j<8;j++){
      int k = kt*32+q*8+j;
      v[j] = (col<3) ? (_Float16)R2[k*3+col] : (_Float16)0.0f;
    }
    *(half8*)&R2f[t*8] = v;
  }
  if (t < 128){ b2f[t]=b2[t]; w3f[t]=W3[t]; }
  __syncthreads();   // the only block-wide barrier

  const int wv = t>>6, l = t&63, l15 = t&15, q4 = (t>>4)&3;
  const int ray = blockIdx.x*RPB + wv;

  // ---- per-ray data (wave-uniform loads)
  float ro0 = rays_o[ray*3+0], ro1 = rays_o[ray*3+1], ro2 = rays_o[ray*3+2];
  float rx  = rays_d[ray*3+0], ry  = rays_d[ray*3+1], rz  = rays_d[ray*3+2];
  float nrm = sqrtf(rx*rx + ry*ry + rz*rz);
  float rd0 = rx/nrm, rd1 = ry/nrm, rd2 = rz/nrm;
  float sfin = s_val[0] * 64.0f;
  float b3v = b3[0];
  float r2lane = (l15==0) ? r2[0] : (l15==1) ? r2[1] : (l15==2) ? r2[2] : 0.0f;

  // affine-collapsed layer-1: lane owns adjacent neurons k0=2l, k1=2l+1
  float u10, v10, u11, v11, uR0, vR0, uR1, vR1;
  {
    int k=2*l;
    float a=W1[k], b=W1[128+k], c=W1[256+k];
    u10 = rd0*a+rd1*b+rd2*c; v10 = ro0*a+ro1*b+ro2*c + b1[k];
    float p=R1[k], qq=R1[128+k], s=R1[256+k], d=R1[384+k], e=R1[512+k], f=R1[640+k];
    uR0 = rd0*p+rd1*qq+rd2*s;
    vR0 = ro0*p+ro1*qq+ro2*s + rd0*d+rd1*e+rd2*f + r1[k];
  }
  {
    int k=2*l+1;
    float a=W1[k], b=W1[128+k], c=W1[256+k];
    u11 = rd0*a+rd1*b+rd2*c; v11 = ro0*a+ro1*b+ro2*c + b1[k];
    float p=R1[k], qq=R1[128+k], s=R1[256+k], d=R1[384+k], e=R1[512+k], f=R1[640+k];
    uR1 = rd0*p+rd1*qq+rd2*s;
    vR1 = ro0*p+ro1*qq+ro2*s + rd0*d+rd1*e+rd2*f + r1[k];
  }

  _Float16* Ahw = &Ah[wv][0];
  float* sD = &sDm[wv][0];
  float* sS = &sSm[wv][0];

  // ---- SDF eval of 16 points: hi/lo fp16 split A, two sequential MFMA passes.
  //      Only ONE A-fragment set (16 VGPRs) live at a time — no spill (R5 shape).
  //      lo recomputed from a re-read of d; B re-read per pass (DS pipe has slack).
  auto eval16 = [&](const float* dptr, float* dstptr){
    // phase 1: stage hi
    {
      const float4* dp4 = (const float4*)dptr;
      float4 dva = dp4[0], dvb = dp4[1], dvc = dp4[2], dvd = dp4[3];
      float dvals[16] = {dva.x,dva.y,dva.z,dva.w, dvb.x,dvb.y,dvb.z,dvb.w,
                         dvc.x,dvc.y,dvc.z,dvc.w, dvd.x,dvd.y,dvd.z,dvd.w};
      #pragma unroll
      for (int m=0;m<16;m++){
        float h0 = fmaxf(fmaf(dvals[m], u10, v10), 0.0f);
        float h1 = fmaxf(fmaf(dvals[m], u11, v11), 0.0f);
        *(half2v*)&Ahw[m*AS + 2*l] = (half2v){(_Float16)h0, (_Float16)h1};
      }
    }
    wsync();
    floatx4 acc[8];
    #pragma unroll
    for (int i=0;i<8;i++) acc[i] = (floatx4){0.f,0.f,0.f,0.f};
    {
      half8 A[4];
      #pragma unroll
      for (int kt=0;kt<4;kt++)
        A[kt] = *(const half8*)&Ahw[l15*AS + kt*32 + q4*8];
      #pragma unroll
      for (int i=0;i<8;i++){
        #pragma unroll
        for (int kt=0;kt<4;kt++){
          half8 B = *(const half8*)&W2f[((i*4+kt)*64 + l)*8];
          acc[i] = __builtin_amdgcn_mfma_f32_16x16x32_f16(A[kt], B, acc[i], 0,0,0);
        }
      }
    }
    wsync();   // hi frags consumed; WAR guard before lo overwrite
    // phase 2: recompute h from d (re-read LDS), stage lo
    {
      const float4* dp4 = (const float4*)dptr;
      float4 dva = dp4[0], dvb = dp4[1], dvc = dp4[2], dvd = dp4[3];
      float dvals[16] = {dva.x,dva.y,dva.z,dva.w, dvb.x,dvb.y,dvb.z,dvb.w,
                         dvc.x,dvc.y,dvc.z,dvc.w, dvd.x,dvd.y,dvd.z,dvd.w};
      #pragma unroll
      for (int m=0;m<16;m++){
        float h0 = fmaxf(fmaf(dvals[m], u10, v10), 0.0f);
        float h1 = fmaxf(fmaf(dvals[m], u11, v11), 0.0f);
        _Float16 hh0 = (_Float16)h0, hh1 = (_Float16)h1;
        *(half2v*)&Ahw[m*AS + 2*l] =
            (half2v){(_Float16)(h0-(float)hh0), (_Float16)(h1-(float)hh1)};
      }
    }
    wsync();
    {
      half8 A[4];
      #pragma unroll
      for (int kt=0;kt<4;kt++)
        A[kt] = *(const half8*)&Ahw[l15*AS + kt*32 + q4*8];
      #pragma unroll
      for (int i=0;i<8;i++){
        #pragma unroll
        for (int kt=0;kt<4;kt++){
          half8 B = *(const half8*)&W2f[((i*4+kt)*64 + l)*8];
          acc[i] = __builtin_amdgcn_mfma_f32_16x16x32_f16(A[kt], B, acc[i], 0,0,0);
        }
      }
    }
    float p0=0.f,p1=0.f,p2=0.f,p3=0.f;
    #pragma unroll
    for (int i=0;i<8;i++){
      float bb = b2f[i*16+l15], ww = w3f[i*16+l15];
      p0 += fmaxf(acc[i][0]+bb,0.0f)*ww;
      p1 += fmaxf(acc[i][1]+bb,0.0f)*ww;
      p2 += fmaxf(acc[i][2]+bb,0.0f)*ww;
      p3 += fmaxf(acc[i][3]+bb,0.0f)*ww;
    }
    #pragma unroll
    for (int off=1; off<16; off<<=1){
      p0 += __shfl_xor(p0, off, 64);
      p1 += __shfl_xor(p1, off, 64);
      p2 += __shfl_xor(p2, off, 64);
      p3 += __shfl_xor(p3, off, 64);
    }
    if (l15==0){
      floatx4 o = {p0+b3v, p1+b3v, p2+b3v, p3+b3v};
      *((floatx4*)&dstptr[q4*4]) = o;
    }
    wsync();
  };

  // ---- initial d: linspace(0.5, 4.0, 64)
  {
    float tt = (float)l / 63.0f;
    sD[l] = 0.5f*(1.0f-tt) + 4.0f*tt;
  }
  wsync();
  for (int c=0;c<4;c++) eval16(&sD[c*16], &sS[c*16]);

  // ---- 4 upsampling iterations (all wave-local; 2 samples/lane: t=l, t=64+l)
  for (int it=0; it<4; it++){
    const int n = 64 + 16*it;
    const int m = n-1;
    const float s_i = 64.0f * (float)(1<<it);

    // load own + neighbor samples
    float dc0 = sD[l],  sc0 = sS[l];
    float dn0 = sD[l+1], snn0 = sS[l+1];
    int lp0 = (l==0)?0:(l-1);
    float dp0 = sD[lp0], sp0 = sS[lp0];
    int i1 = 64+l;
    float dc1 = sD[i1 & 127], sc1 = sS[i1 & 127];
    int i1n = (i1+1) & 127;
    float dn1 = sD[i1n], snn1 = sS[i1n];
    float dp1 = sD[(i1-1) & 127], sp1 = sS[(i1-1) & 127];

    auto alpha_at = [&](float dp, float dc, float dn, float sp, float sc, float sn,
                        bool hasprev)->float{
      float mid = 0.5f*(sc+sn);
      float dv = (sn-sc)/(dn-dc+1e-5f);
      float pdv = hasprev ? (sc-sp)/(dc-dp+1e-5f) : 0.0f;
      float d2 = fminf(fminf(pdv,dv), 0.0f); d2 = fmaxf(d2,-10.0f);
      float dist = dn-dc;
      float pe = mid - d2*dist*0.5f, ne = mid + d2*dist*0.5f;
      float pc = sigm(pe*s_i), nc = sigm(ne*s_i);
      return (pc-nc+1e-5f)/(pc+1e-5f);
    };
    bool va0 = (l < m), va1 = (i1 < m);
    float a0 = va0 ? alpha_at(dp0,dc0,dn0,sp0,sc0,snn0, l>0)  : 0.0f;
    float a1 = va1 ? alpha_at(dp1,dc1,dn1,sp1,sc1,snn1, true) : 0.0f;

    // exclusive cumprod of (1-a+1e-10) over m entries
    float g0 = va0 ? (1.0f-a0+1e-10f) : 1.0f;
    float g1 = va1 ? (1.0f-a1+1e-10f) : 1.0f;
    #pragma unroll
    for (int off=1; off<64; off<<=1){ float y=__shfl_up(g0,off,64); if (l>=off) g0*=y; }
    float gtot0 = __shfl(g0, 63, 64);
    #pragma unroll
    for (int off=1; off<64; off<<=1){ float y=__shfl_up(g1,off,64); if (l>=off) g1*=y; }
    g1 *= gtot0;
    float T0 = __shfl_up(g0, 1, 64); if (l==0) T0 = 1.0f;
    float T1 = __shfl_up(g1, 1, 64); if (l==0) T1 = gtot0;

    // weights + inclusive cumsum
    float w0 = va0 ? (a0*T0 + 1e-5f) : 0.0f;
    float w1 = va1 ? (a1*T1 + 1e-5f) : 0.0f;
    #pragma unroll
    for (int off=1; off<64; off<<=1){ float y=__shfl_up(w0,off,64); if (l>=off) w0+=y; }
    float wtot0 = __shfl(w0, 63, 64);
    #pragma unroll
    for (int off=1; off<64; off<<=1){ float y=__shfl_up(w1,off,64); if (l>=off) w1+=y; }
    w1 += wtot0;
    float S = (m-1 < 64) ? __shfl(w0, m-1, 64) : __shfl(w1, m-65, 64);

    // cdf[t] = t==0 ? 0 : cs[t-1]/S  (length n)
    float csp0 = __shfl_up(w0, 1, 64);
    float cdf0 = (l==0) ? 0.0f : csp0/S;
    float csp1 = __shfl_up(w1, 1, 64);
    float c63  = __shfl(w0, 63, 64);
    float cdf1r = ((l==0) ? c63 : csp1)/S;
    float cdf1m = (i1 < n) ? cdf1r : 2.0f;

    // searchsorted-right for u_q = q/15, q=0..15 (ballot count)
    int ind = 0;
    #pragma unroll
    for (int q=0;q<16;q++){
      float u = (float)q/15.0f;
      unsigned long long bq0 = __ballot(cdf0 <= u);
      unsigned long long bq1 = __ballot(cdf1m <= u);
      int c = __popcll(bq0) + __popcll(bq1);
      if (l==q) ind = c;
    }
    // interp (meaningful on lanes 0..15; others compute garbage harmlessly)
    {
      float u = (float)l15/15.0f;
      int below = ind-1; if (below<0) below=0; if (below>n-1) below=n-1;
      int above = ind;   if (above>n-1) above=n-1;
      float cb = (below<64) ? __shfl(cdf0, below, 64) : __shfl(cdf1r, below-64, 64);
      float ca = (above<64) ? __shfl(cdf0, above, 64) : __shfl(cdf1r, above-64, 64);
      float bb = sD[below], ba = sD[above];
      float den = ca - cb; if (den < 1e-5f) den = 1.0f;
      float tt = (u - cb)/den;
      float fdnew = bb + tt*(ba-bb);
      if (l < 16) fDs[wv][l] = fdnew;
    }
    wsync();

    eval16(&fDs[wv][0], &fSs[wv][0]);

    // stable merge: ranks via compares/ballots, scatter via LDS
    {
      const float4* fp4 = (const float4*)&fDs[wv][0];
      float4 fa = fp4[0], fb = fp4[1], fc = fp4[2], fd = fp4[3];
      float fq[16] = {fa.x,fa.y,fa.z,fa.w, fb.x,fb.y,fb.z,fb.w,
                      fc.x,fc.y,fc.z,fc.w, fd.x,fd.y,fd.z,fd.w};
      float fdv = fDs[wv][l15];
      float fsv = fSs[wv][l15];
      bool v1 = (i1 < n);
      int rold0 = l, rold1 = i1;
      #pragma unroll
      for (int q=0;q<16;q++){
        rold0 += (fq[q] < dc0) ? 1 : 0;
        rold1 += (fq[q] < dc1) ? 1 : 0;
      }
      int rf = 0;
      #pragma unroll
      for (int q=0;q<16;q++){
        unsigned long long bq0 = __ballot(dc0 <= fq[q]);
        unsigned long long bq1 = __ballot(v1 && (dc1 <= fq[q]));
        int c = q + __popcll(bq0) + __popcll(bq1);
        if (l==q) rf = c;
      }
      wsync();
      sD[rold0] = dc0; sS[rold0] = sc0;
      if (v1){ sD[rold1] = dc1; sS[rold1] = sc1; }
      if (l < 16){ sD[rf] = fdv; sS[rf] = fsv; }
      wsync();
    }
  }

  // ---- final compositing (sdf_final == carried sS; n = 128)
  float dm0, dm1, vw0, vw1;
  {
    float d0 = sD[l],  d1 = sD[64+l];
    float s0 = sS[l],  s1 = sS[64+l];
    float dn0 = sD[l+1], sn0 = sS[l+1];
    int i1n = (65+l) & 127;
    float dn1 = sD[i1n], sn1 = sS[i1n];
    bool v1a = (l < 63);                       // t=64+l < 127
    float cf0 = sigm(s0*sfin), cfn0 = sigm(sn0*sfin);
    float a0 = (cf0-cfn0+1e-5f)/(cf0+1e-5f);
    a0 = fminf(fmaxf(a0,0.0f),1.0f);
    float cf1 = sigm(s1*sfin), cfn1 = sigm(sn1*sfin);
    float a1 = (cf1-cfn1+1e-5f)/(cf1+1e-5f);
    a1 = v1a ? fminf(fmaxf(a1,0.0f),1.0f) : 0.0f;
    dm0 = 0.5f*(d0+dn0);
    dm1 = v1a ? 0.5f*(d1+dn1) : 0.0f;

    float g0 = 1.0f-a0+1e-10f;
    float g1 = v1a ? (1.0f-a1+1e-10f) : 1.0f;
    #pragma unroll
    for (int off=1; off<64; off<<=1){ float y=__shfl_up(g0,off,64); if (l>=off) g0*=y; }
    float gtot0 = __shfl(g0, 63, 64);
    #pragma unroll
    for (int off=1; off<64; off<<=1){ float y=__shfl_up(g1,off,64); if (l>=off) g1*=y; }
    g1 *= gtot0;
    float T0 = __shfl_up(g0, 1, 64); if (l==0) T0 = 1.0f;
    float T1 = __shfl_up(g1, 1, 64); if (l==0) T1 = gtot0;
    vw0 = a0*T0;
    vw1 = a1*T1;
    wsync();
    sD[l] = dm0; sD[64+l] = dm1;               // overwrite: sD := d_mid, sS := vis_w
    sS[l] = vw0; sS[64+l] = vw1;
    wsync();
  }

  // ---- radiance net: 8 tiles of 16 points, wave-local MFMA (fp16-single A)
  half8 RB[4];
  #pragma unroll
  for (int kt=0;kt<4;kt++) RB[kt] = *(const half8*)&R2f[(kt*64+l)*8];
  float rgb = 0.0f;
  for (int g=0; g<8; g++){
    const float4* dp4 = (const float4*)&sDm[wv][g*16];
    float4 dva = dp4[0], dvb = dp4[1], dvc = dp4[2], dvd = dp4[3];
    float dvals[16] = {dva.x,dva.y,dva.z,dva.w, dvb.x,dvb.y,dvb.z,dvb.w,
                       dvc.x,dvc.y,dvc.z,dvc.w, dvd.x,dvd.y,dvd.z,dvd.w};
    #pragma unroll
    for (int m=0;m<16;m++){
      float h0 = fmaxf(fmaf(dvals[m], uR0, vR0), 0.0f);
      float h1 = fmaxf(fmaf(dvals[m], uR1, vR1), 0.0f);
      *(half2v*)&Ahw[m*AS + 2*l] = (half2v){(_Float16)h0, (_Float16)h1};
    }
    wsync();
    half8 A[4];
    #pragma unroll
    for (int kt=0;kt<4;kt++)
      A[kt] = *(const half8*)&Ahw[l15*AS + kt*32 + q4*8];
    floatx4 racc = (floatx4){0.f,0.f,0.f,0.f};
    #pragma unroll
    for (int kt=0;kt<4;kt++)
      racc = __builtin_amdgcn_mfma_f32_16x16x32_f16(A[kt], RB[kt], racc, 0,0,0);
    #pragma unroll
    for (int r=0;r<4;r++){
      int pt = g*16 + q4*4 + r;
      float w = sS[pt];
      rgb += w * sigm(racc[r] + r2lane);
    }
    wsync();
  }

  // ---- reductions + output
  float v3 = dm0*vw0 + dm1*vw1;
  float v4 = vw0 + vw1;
  #pragma unroll
  for (int off=32; off>=1; off>>=1){
    v3 += __shfl_xor(v3, off, 64);
    v4 += __shfl_xor(v4, off, 64);
  }
  rgb += __shfl_xor(rgb, 16, 64);
  rgb += __shfl_xor(rgb, 32, 64);
  if (l < 3)  out[ray*5 + l] = rgb;
  if (l == 3) out[ray*5 + 3] = v3;
  if (l == 4) out[ray*5 + 4] = v4;
}

extern "C" void kernel_launch(void* const* d_in, const int* in_sizes, int n_in,
                              void* d_out, int out_size, void* d_ws, size_t ws_size,
                              hipStream_t stream) {
  const float* rays_o = (const float*)d_in[0];
  const float* rays_d = (const float*)d_in[1];
  const float* W1 = (const float*)d_in[2];
  const float* b1 = (const float*)d_in[3];
  const float* W2 = (const float*)d_in[4];
  const float* b2 = (const float*)d_in[5];
  const float* W3 = (const float*)d_in[6];
  const float* b3 = (const float*)d_in[7];
  const float* R1 = (const float*)d_in[8];
  const float* r1 = (const float*)d_in[9];
  const float* R2 = (const float*)d_in[10];
  const float* r2 = (const float*)d_in[11];
  const float* sv = (const float*)d_in[12];
  float* out = (float*)d_out;
  neus_render_kernel<<<NRAYS/RPB, 512, 0, stream>>>(
      rays_o, rays_d, W1, b1, W2, b2, W3, b3, R1, r1, R2, r2, sv, out);
}

// Round 9
// 209.137 us; speedup vs baseline: 1.0105x; 1.0105x over previous
//
#include <hip/hip_runtime.h>
#include <math.h>

#define NRAYS 8192
#define RPB 8              // rays (= waves) per block
#define AS 136             // Ah row stride in f16 elems (pad vs 128 to spread banks)

typedef _Float16 half8 __attribute__((ext_vector_type(8)));
typedef _Float16 half2v __attribute__((ext_vector_type(2)));
typedef float floatx4 __attribute__((ext_vector_type(4)));

__device__ __forceinline__ float sigm(float x){ return 1.0f/(1.0f + __expf(-x)); }

// wave-local LDS sync: drain this wave's DS ops; no cross-wave barrier.
__device__ __forceinline__ void wsync(){
  __builtin_amdgcn_wave_barrier();
  __builtin_amdgcn_s_waitcnt(0xc07f);   // lgkmcnt(0) only
  __builtin_amdgcn_wave_barrier();
}

__launch_bounds__(512, 4)
__global__ void neus_render_kernel(
    const float* __restrict__ rays_o, const float* __restrict__ rays_d,
    const float* __restrict__ W1, const float* __restrict__ b1,
    const float* __restrict__ W2, const float* __restrict__ b2,
    const float* __restrict__ W3, const float* __restrict__ b3,
    const float* __restrict__ R1, const float* __restrict__ r1,
    const float* __restrict__ R2, const float* __restrict__ r2,
    const float* __restrict__ s_val, float* __restrict__ out)
{
  // ---- shared: weights (block-shared) + per-ray scratch. Total = 80 KB exactly.
  __shared__ __align__(16) _Float16 W2f[2048*8];     // 32 KB: 32 B-frags x 64 lanes x 8
  __shared__ __align__(16) _Float16 R2f[256*8];      // 4 KB
  __shared__ __align__(16) _Float16 Ah[RPB][16*AS];  // 34 KB: per-ray A staging
  __shared__ __align__(16) float sDm[RPB][128];      // 4 KB
  __shared__ __align__(16) float sSm[RPB][128];      // 4 KB
  __shared__ __align__(16) float fDs[RPB][16];       // 512 B
  __shared__ __align__(16) float fSs[RPB][16];       // 512 B
  __shared__ float b2f[128], w3f[128];               // 1 KB

  const int t = threadIdx.x;

  // ---- cooperative weight staging (only cross-wave cooperation in the kernel)
  #pragma unroll
  for (int r=0;r<4;r++){
    int row = t + r*512;                 // 0..2047: frag-major rows
    int i = row>>8, kt=(row>>6)&3, lr=row&63;
    int q = lr>>4, n = i*16 + (lr&15);
    half8 v;
    #pragma unroll
    for (int j=0;j<8;j++) v[j] = (_Float16)W2[(kt*32+q*8+j)*128 + n];
    *(half8*)&W2f[row*8] = v;
  }
  if (t < 256){
    int kt=t>>6, lr=t&63, q=lr>>4, col=lr&15;
    half8 v;
    #pragma unroll
    for (int j=0;j<8;j++){
      int k = kt*32+q*8+j;
      v[j] = (col<3) ? (_Float16)R2[k*3+col] : (_Float16)0.0f;
    }
    *(half8*)&R2f[t*8] = v;
  }
  if (t < 128){ b2f[t]=b2[t]; w3f[t]=W3[t]; }
  __syncthreads();   // the only block-wide barrier

  const int wv = t>>6, l = t&63, l15 = t&15, q4 = (t>>4)&3;
  const int ray = blockIdx.x*RPB + wv;

  // ---- per-ray data (wave-uniform loads)
  float ro0 = rays_o[ray*3+0], ro1 = rays_o[ray*3+1], ro2 = rays_o[ray*3+2];
  float rx  = rays_d[ray*3+0], ry  = rays_d[ray*3+1], rz  = rays_d[ray*3+2];
  float nrm = sqrtf(rx*rx + ry*ry + rz*rz);
  float rd0 = rx/nrm, rd1 = ry/nrm, rd2 = rz/nrm;
  float sfin = s_val[0] * 64.0f;
  float b3v = b3[0];
  float r2lane = (l15==0) ? r2[0] : (l15==1) ? r2[1] : (l15==2) ? r2[2] : 0.0f;

  // affine-collapsed layer-1: lane owns adjacent neurons k0=2l, k1=2l+1
  float u10, v10, u11, v11, uR0, vR0, uR1, vR1;
  {
    int k=2*l;
    float a=W1[k], b=W1[128+k], c=W1[256+k];
    u10 = rd0*a+rd1*b+rd2*c; v10 = ro0*a+ro1*b+ro2*c + b1[k];
    float p=R1[k], qq=R1[128+k], s=R1[256+k], d=R1[384+k], e=R1[512+k], f=R1[640+k];
    uR0 = rd0*p+rd1*qq+rd2*s;
    vR0 = ro0*p+ro1*qq+ro2*s + rd0*d+rd1*e+rd2*f + r1[k];
  }
  {
    int k=2*l+1;
    float a=W1[k], b=W1[128+k], c=W1[256+k];
    u11 = rd0*a+rd1*b+rd2*c; v11 = ro0*a+ro1*b+ro2*c + b1[k];
    float p=R1[k], qq=R1[128+k], s=R1[256+k], d=R1[384+k], e=R1[512+k], f=R1[640+k];
    uR1 = rd0*p+rd1*qq+rd2*s;
    vR1 = ro0*p+ro1*qq+ro2*s + rd0*d+rd1*e+rd2*f + r1[k];
  }

  _Float16* Ahw = &Ah[wv][0];
  float* sD = &sDm[wv][0];
  float* sS = &sSm[wv][0];

  // ---- SDF eval of 16 points: hi/lo fp16 split A, two sequential MFMA passes.
  //      Staging works 4 points at a time (ONE float4 live, not dvals[16]) —
  //      peak VGPR pressure stays at the R5 (no-spill) level.
  auto eval16 = [&](const float* dptr, float* dstptr){
    // phase 1: stage hi (4-at-a-time)
    #pragma unroll
    for (int mq=0;mq<4;mq++){
      float4 dv4 = ((const float4*)dptr)[mq];
      float h;
      h = fmaxf(fmaf(dv4.x, u10, v10), 0.0f);
      Ahw[(mq*4+0)*AS + 2*l] = (_Float16)h;
      h = fmaxf(fmaf(dv4.x, u11, v11), 0.0f);
      Ahw[(mq*4+0)*AS + 2*l+1] = (_Float16)h;
      h = fmaxf(fmaf(dv4.y, u10, v10), 0.0f);
      Ahw[(mq*4+1)*AS + 2*l] = (_Float16)h;
      h = fmaxf(fmaf(dv4.y, u11, v11), 0.0f);
      Ahw[(mq*4+1)*AS + 2*l+1] = (_Float16)h;
      h = fmaxf(fmaf(dv4.z, u10, v10), 0.0f);
      Ahw[(mq*4+2)*AS + 2*l] = (_Float16)h;
      h = fmaxf(fmaf(dv4.z, u11, v11), 0.0f);
      Ahw[(mq*4+2)*AS + 2*l+1] = (_Float16)h;
      h = fmaxf(fmaf(dv4.w, u10, v10), 0.0f);
      Ahw[(mq*4+3)*AS + 2*l] = (_Float16)h;
      h = fmaxf(fmaf(dv4.w, u11, v11), 0.0f);
      Ahw[(mq*4+3)*AS + 2*l+1] = (_Float16)h;
    }
    wsync();
    floatx4 acc[8];
    #pragma unroll
    for (int i=0;i<8;i++) acc[i] = (floatx4){0.f,0.f,0.f,0.f};
    {
      half8 A[4];
      #pragma unroll
      for (int kt=0;kt<4;kt++)
        A[kt] = *(const half8*)&Ahw[l15*AS + kt*32 + q4*8];
      #pragma unroll
      for (int i=0;i<8;i++){
        #pragma unroll
        for (int kt=0;kt<4;kt++){
          half8 B = *(const half8*)&W2f[((i*4+kt)*64 + l)*8];
          acc[i] = __builtin_amdgcn_mfma_f32_16x16x32_f16(A[kt], B, acc[i], 0,0,0);
        }
      }
    }
    wsync();   // hi frags consumed; WAR guard before lo overwrite
    // phase 2: recompute h from d, stage lo (4-at-a-time)
    #pragma unroll
    for (int mq=0;mq<4;mq++){
      float4 dv4 = ((const float4*)dptr)[mq];
      float h; _Float16 hh;
      h = fmaxf(fmaf(dv4.x, u10, v10), 0.0f); hh = (_Float16)h;
      Ahw[(mq*4+0)*AS + 2*l] = (_Float16)(h-(float)hh);
      h = fmaxf(fmaf(dv4.x, u11, v11), 0.0f); hh = (_Float16)h;
      Ahw[(mq*4+0)*AS + 2*l+1] = (_Float16)(h-(float)hh);
      h = fmaxf(fmaf(dv4.y, u10, v10), 0.0f); hh = (_Float16)h;
      Ahw[(mq*4+1)*AS + 2*l] = (_Float16)(h-(float)hh);
      h = fmaxf(fmaf(dv4.y, u11, v11), 0.0f); hh = (_Float16)h;
      Ahw[(mq*4+1)*AS + 2*l+1] = (_Float16)(h-(float)hh);
      h = fmaxf(fmaf(dv4.z, u10, v10), 0.0f); hh = (_Float16)h;
      Ahw[(mq*4+2)*AS + 2*l] = (_Float16)(h-(float)hh);
      h = fmaxf(fmaf(dv4.z, u11, v11), 0.0f); hh = (_Float16)h;
      Ahw[(mq*4+2)*AS + 2*l+1] = (_Float16)(h-(float)hh);
      h = fmaxf(fmaf(dv4.w, u10, v10), 0.0f); hh = (_Float16)h;
      Ahw[(mq*4+3)*AS + 2*l] = (_Float16)(h-(float)hh);
      h = fmaxf(fmaf(dv4.w, u11, v11), 0.0f); hh = (_Float16)h;
      Ahw[(mq*4+3)*AS + 2*l+1] = (_Float16)(h-(float)hh);
    }
    wsync();
    {
      half8 A[4];
      #pragma unroll
      for (int kt=0;kt<4;kt++)
        A[kt] = *(const half8*)&Ahw[l15*AS + kt*32 + q4*8];
      #pragma unroll
      for (int i=0;i<8;i++){
        #pragma unroll
        for (int kt=0;kt<4;kt++){
          half8 B = *(const half8*)&W2f[((i*4+kt)*64 + l)*8];
          acc[i] = __builtin_amdgcn_mfma_f32_16x16x32_f16(A[kt], B, acc[i], 0,0,0);
        }
      }
    }
    float p0=0.f,p1=0.f,p2=0.f,p3=0.f;
    #pragma unroll
    for (int i=0;i<8;i++){
      float bb = b2f[i*16+l15], ww = w3f[i*16+l15];
      p0 += fmaxf(acc[i][0]+bb,0.0f)*ww;
      p1 += fmaxf(acc[i][1]+bb,0.0f)*ww;
      p2 += fmaxf(acc[i][2]+bb,0.0f)*ww;
      p3 += fmaxf(acc[i][3]+bb,0.0f)*ww;
    }
    #pragma unroll
    for (int off=1; off<16; off<<=1){
      p0 += __shfl_xor(p0, off, 64);
      p1 += __shfl_xor(p1, off, 64);
      p2 += __shfl_xor(p2, off, 64);
      p3 += __shfl_xor(p3, off, 64);
    }
    if (l15==0){
      floatx4 o = {p0+b3v, p1+b3v, p2+b3v, p3+b3v};
      *((floatx4*)&dstptr[q4*4]) = o;
    }
    wsync();
  };

  // ---- initial d: linspace(0.5, 4.0, 64)
  {
    float tt = (float)l / 63.0f;
    sD[l] = 0.5f*(1.0f-tt) + 4.0f*tt;
  }
  wsync();
  for (int c=0;c<4;c++) eval16(&sD[c*16], &sS[c*16]);

  // ---- 4 upsampling iterations (all wave-local; 2 samples/lane: t=l, t=64+l)
  for (int it=0; it<4; it++){
    const int n = 64 + 16*it;
    const int m = n-1;
    const float s_i = 64.0f * (float)(1<<it);

    // load own + neighbor samples
    float dc0 = sD[l],  sc0 = sS[l];
    float dn0 = sD[l+1], snn0 = sS[l+1];
    int lp0 = (l==0)?0:(l-1);
    float dp0 = sD[lp0], sp0 = sS[lp0];
    int i1 = 64+l;
    float dc1 = sD[i1 & 127], sc1 = sS[i1 & 127];
    int i1n = (i1+1) & 127;
    float dn1 = sD[i1n], snn1 = sS[i1n];
    float dp1 = sD[(i1-1) & 127], sp1 = sS[(i1-1) & 127];

    auto alpha_at = [&](float dp, float dc, float dn, float sp, float sc, float sn,
                        bool hasprev)->float{
      float mid = 0.5f*(sc+sn);
      float dv = (sn-sc)/(dn-dc+1e-5f);
      float pdv = hasprev ? (sc-sp)/(dc-dp+1e-5f) : 0.0f;
      float d2 = fminf(fminf(pdv,dv), 0.0f); d2 = fmaxf(d2,-10.0f);
      float dist = dn-dc;
      float pe = mid - d2*dist*0.5f, ne = mid + d2*dist*0.5f;
      float pc = sigm(pe*s_i), nc = sigm(ne*s_i);
      return (pc-nc+1e-5f)/(pc+1e-5f);
    };
    bool va0 = (l < m), va1 = (i1 < m);
    float a0 = va0 ? alpha_at(dp0,dc0,dn0,sp0,sc0,snn0, l>0)  : 0.0f;
    float a1 = va1 ? alpha_at(dp1,dc1,dn1,sp1,sc1,snn1, true) : 0.0f;

    // exclusive cumprod of (1-a+1e-10) over m entries
    float g0 = va0 ? (1.0f-a0+1e-10f) : 1.0f;
    float g1 = va1 ? (1.0f-a1+1e-10f) : 1.0f;
    #pragma unroll
    for (int off=1; off<64; off<<=1){ float y=__shfl_up(g0,off,64); if (l>=off) g0*=y; }
    float gtot0 = __shfl(g0, 63, 64);
    #pragma unroll
    for (int off=1; off<64; off<<=1){ float y=__shfl_up(g1,off,64); if (l>=off) g1*=y; }
    g1 *= gtot0;
    float T0 = __shfl_up(g0, 1, 64); if (l==0) T0 = 1.0f;
    float T1 = __shfl_up(g1, 1, 64); if (l==0) T1 = gtot0;

    // weights + inclusive cumsum
    float w0 = va0 ? (a0*T0 + 1e-5f) : 0.0f;
    float w1 = va1 ? (a1*T1 + 1e-5f) : 0.0f;
    #pragma unroll
    for (int off=1; off<64; off<<=1){ float y=__shfl_up(w0,off,64); if (l>=off) w0+=y; }
    float wtot0 = __shfl(w0, 63, 64);
    #pragma unroll
    for (int off=1; off<64; off<<=1){ float y=__shfl_up(w1,off,64); if (l>=off) w1+=y; }
    w1 += wtot0;
    float S = (m-1 < 64) ? __shfl(w0, m-1, 64) : __shfl(w1, m-65, 64);

    // cdf[t] = t==0 ? 0 : cs[t-1]/S  (length n)
    float csp0 = __shfl_up(w0, 1, 64);
    float cdf0 = (l==0) ? 0.0f : csp0/S;
    float csp1 = __shfl_up(w1, 1, 64);
    float c63  = __shfl(w0, 63, 64);
    float cdf1r = ((l==0) ? c63 : csp1)/S;
    float cdf1m = (i1 < n) ? cdf1r : 2.0f;

    // searchsorted-right for u_q = q/15, q=0..15 (ballot count)
    int ind = 0;
    #pragma unroll
    for (int q=0;q<16;q++){
      float u = (float)q/15.0f;
      unsigned long long bq0 = __ballot(cdf0 <= u);
      unsigned long long bq1 = __ballot(cdf1m <= u);
      int c = __popcll(bq0) + __popcll(bq1);
      if (l==q) ind = c;
    }
    // interp (meaningful on lanes 0..15; others compute garbage harmlessly)
    {
      float u = (float)l15/15.0f;
      int below = ind-1; if (below<0) below=0; if (below>n-1) below=n-1;
      int above = ind;   if (above>n-1) above=n-1;
      float cb = (below<64) ? __shfl(cdf0, below, 64) : __shfl(cdf1r, below-64, 64);
      float ca = (above<64) ? __shfl(cdf0, above, 64) : __shfl(cdf1r, above-64, 64);
      float bb = sD[below], ba = sD[above];
      float den = ca - cb; if (den < 1e-5f) den = 1.0f;
      float tt = (u - cb)/den;
      float fdnew = bb + tt*(ba-bb);
      if (l < 16) fDs[wv][l] = fdnew;
    }
    wsync();

    eval16(&fDs[wv][0], &fSs[wv][0]);

    // stable merge: ranks via compares/ballots, scatter via LDS
    {
      const float4* fp4 = (const float4*)&fDs[wv][0];
      float4 fa = fp4[0], fb = fp4[1], fc = fp4[2], fd = fp4[3];
      float fq[16] = {fa.x,fa.y,fa.z,fa.w, fb.x,fb.y,fb.z,fb.w,
                      fc.x,fc.y,fc.z,fc.w, fd.x,fd.y,fd.z,fd.w};
      float fdv = fDs[wv][l15];
      float fsv = fSs[wv][l15];
      bool v1 = (i1 < n);
      int rold0 = l, rold1 = i1;
      #pragma unroll
      for (int q=0;q<16;q++){
        rold0 += (fq[q] < dc0) ? 1 : 0;
        rold1 += (fq[q] < dc1) ? 1 : 0;
      }
      int rf = 0;
      #pragma unroll
      for (int q=0;q<16;q++){
        unsigned long long bq0 = __ballot(dc0 <= fq[q]);
        unsigned long long bq1 = __ballot(v1 && (dc1 <= fq[q]));
        int c = q + __popcll(bq0) + __popcll(bq1);
        if (l==q) rf = c;
      }
      wsync();
      sD[rold0] = dc0; sS[rold0] = sc0;
      if (v1){ sD[rold1] = dc1; sS[rold1] = sc1; }
      if (l < 16){ sD[rf] = fdv; sS[rf] = fsv; }
      wsync();
    }
  }

  // ---- final compositing (sdf_final == carried sS; n = 128)
  float dm0, dm1, vw0, vw1;
  {
    float d0 = sD[l],  d1 = sD[64+l];
    float s0 = sS[l],  s1 = sS[64+l];
    float dn0 = sD[l+1], sn0 = sS[l+1];
    int i1n = (65+l) & 127;
    float dn1 = sD[i1n], sn1 = sS[i1n];
    bool v1a = (l < 63);                       // t=64+l < 127
    float cf0 = sigm(s0*sfin), cfn0 = sigm(sn0*sfin);
    float a0 = (cf0-cfn0+1e-5f)/(cf0+1e-5f);
    a0 = fminf(fmaxf(a0,0.0f),1.0f);
    float cf1 = sigm(s1*sfin), cfn1 = sigm(sn1*sfin);
    float a1 = (cf1-cfn1+1e-5f)/(cf1+1e-5f);
    a1 = v1a ? fminf(fmaxf(a1,0.0f),1.0f) : 0.0f;
    dm0 = 0.5f*(d0+dn0);
    dm1 = v1a ? 0.5f*(d1+dn1) : 0.0f;

    float g0 = 1.0f-a0+1e-10f;
    float g1 = v1a ? (1.0f-a1+1e-10f) : 1.0f;
    #pragma unroll
    for (int off=1; off<64; off<<=1){ float y=__shfl_up(g0,off,64); if (l>=off) g0*=y; }
    float gtot0 = __shfl(g0, 63, 64);
    #pragma unroll
    for (int off=1; off<64; off<<=1){ float y=__shfl_up(g1,off,64); if (l>=off) g1*=y; }
    g1 *= gtot0;
    float T0 = __shfl_up(g0, 1, 64); if (l==0) T0 = 1.0f;
    float T1 = __shfl_up(g1, 1, 64); if (l==0) T1 = gtot0;
    vw0 = a0*T0;
    vw1 = a1*T1;
    wsync();
    sD[l] = dm0; sD[64+l] = dm1;               // overwrite: sD := d_mid, sS := vis_w
    sS[l] = vw0; sS[64+l] = vw1;
    wsync();
  }

  // ---- radiance net: 8 tiles of 16 points, wave-local MFMA (fp16-single A),
  //      staging 4 points at a time
  half8 RB[4];
  #pragma unroll
  for (int kt=0;kt<4;kt++) RB[kt] = *(const half8*)&R2f[(kt*64+l)*8];
  float rgb = 0.0f;
  for (int g=0; g<8; g++){
    #pragma unroll
    for (int mq=0;mq<4;mq++){
      float4 dv4 = ((const float4*)&sDm[wv][g*16])[mq];
      float h;
      h = fmaxf(fmaf(dv4.x, uR0, vR0), 0.0f);
      Ahw[(mq*4+0)*AS + 2*l] = (_Float16)h;
      h = fmaxf(fmaf(dv4.x, uR1, vR1), 0.0f);
      Ahw[(mq*4+0)*AS + 2*l+1] = (_Float16)h;
      h = fmaxf(fmaf(dv4.y, uR0, vR0), 0.0f);
      Ahw[(mq*4+1)*AS + 2*l] = (_Float16)h;
      h = fmaxf(fmaf(dv4.y, uR1, vR1), 0.0f);
      Ahw[(mq*4+1)*AS + 2*l+1] = (_Float16)h;
      h = fmaxf(fmaf(dv4.z, uR0, vR0), 0.0f);
      Ahw[(mq*4+2)*AS + 2*l] = (_Float16)h;
      h = fmaxf(fmaf(dv4.z, uR1, vR1), 0.0f);
      Ahw[(mq*4+2)*AS + 2*l+1] = (_Float16)h;
      h = fmaxf(fmaf(dv4.w, uR0, vR0), 0.0f);
      Ahw[(mq*4+3)*AS + 2*l] = (_Float16)h;
      h = fmaxf(fmaf(dv4.w, uR1, vR1), 0.0f);
      Ahw[(mq*4+3)*AS + 2*l+1] = (_Float16)h;
    }
    wsync();
    half8 A[4];
    #pragma unroll
    for (int kt=0;kt<4;kt++)
      A[kt] = *(const half8*)&Ahw[l15*AS + kt*32 + q4*8];
    floatx4 racc = (floatx4){0.f,0.f,0.f,0.f};
    #pragma unroll
    for (int kt=0;kt<4;kt++)
      racc = __builtin_amdgcn_mfma_f32_16x16x32_f16(A[kt], RB[kt], racc, 0,0,0);
    #pragma unroll
    for (int r=0;r<4;r++){
      int pt = g*16 + q4*4 + r;
      float w = sS[pt];
      rgb += w * sigm(racc[r] + r2lane);
    }
    wsync();
  }

  // ---- reductions + output
  float v3 = dm0*vw0 + dm1*vw1;
  float v4 = vw0 + vw1;
  #pragma unroll
  for (int off=32; off>=1; off>>=1){
    v3 += __shfl_xor(v3, off, 64);
    v4 += __shfl_xor(v4, off, 64);
  }
  rgb += __shfl_xor(rgb, 16, 64);
  rgb += __shfl_xor(rgb, 32, 64);
  if (l < 3)  out[ray*5 + l] = rgb;
  if (l == 3) out[ray*5 + 3] = v3;
  if (l == 4) out[ray*5 + 4] = v4;
}

extern "C" void kernel_launch(void* const* d_in, const int* in_sizes, int n_in,
                              void* d_out, int out_size, void* d_ws, size_t ws_size,
                              hipStream_t stream) {
  const float* rays_o = (const float*)d_in[0];
  const float* rays_d = (const float*)d_in[1];
  const float* W1 = (const float*)d_in[2];
  const float* b1 = (const float*)d_in[3];
  const float* W2 = (const float*)d_in[4];
  const float* b2 = (const float*)d_in[5];
  const float* W3 = (const float*)d_in[6];
  const float* b3 = (const float*)d_in[7];
  const float* R1 = (const float*)d_in[8];
  const float* r1 = (const float*)d_in[9];
  const float* R2 = (const float*)d_in[10];
  const float* r2 = (const float*)d_in[11];
  const float* sv = (const float*)d_in[12];
  float* out = (float*)d_out;
  neus_render_kernel<<<NRAYS/RPB, 512, 0, stream>>>(
      rays_o, rays_d, W1, b1, W2, b2, W3, b3, R1, r1, R2, r2, sv, out);
}

// Round 10
// 202.789 us; speedup vs baseline: 1.0421x; 1.0313x over previous
//
#include <hip/hip_runtime.h>
#include <math.h>

#define NRAYS 8192
#define RPB 8              // rays (= waves) per block
#define AS 136             // Ah row stride in f16 elems (pad vs 128 to spread banks)

typedef _Float16 half8 __attribute__((ext_vector_type(8)));
typedef _Float16 half2v __attribute__((ext_vector_type(2)));
typedef float floatx4 __attribute__((ext_vector_type(4)));

__device__ __forceinline__ float sigm(float x){ return 1.0f/(1.0f + __expf(-x)); }

// wave-local LDS sync: drain this wave's DS ops; no cross-wave barrier.
__device__ __forceinline__ void wsync(){
  __builtin_amdgcn_wave_barrier();
  __builtin_amdgcn_s_waitcnt(0xc07f);   // lgkmcnt(0) only
  __builtin_amdgcn_wave_barrier();
}

// ---- SDF eval of 16 points as a MACRO: guaranteed inline (no lambda-ABI call,
//      no caller-saved spill around 12 call sites — R6-R9 spill suspect #1).
//      hi/lo fp16 split A; fused B-loop: each W2 B-frag read ONCE, used for
//      hi+lo MFMAs (R7's 40-ds_read shape) but only Ahi(16)+Alo_kt(4) regs live.
#define EVAL16(dptr_, dstptr_) do { \
  const float* dp_ = (dptr_); \
  _Pragma("unroll") \
  for (int mq=0;mq<4;mq++){ \
    float4 dv4 = ((const float4*)dp_)[mq]; \
    float h0_, h1_; \
    h0_ = fmaxf(fmaf(dv4.x, u10, v10), 0.0f); h1_ = fmaxf(fmaf(dv4.x, u11, v11), 0.0f); \
    *(half2v*)&Ahw[(mq*4+0)*AS + 2*l] = (half2v){(_Float16)h0_, (_Float16)h1_}; \
    h0_ = fmaxf(fmaf(dv4.y, u10, v10), 0.0f); h1_ = fmaxf(fmaf(dv4.y, u11, v11), 0.0f); \
    *(half2v*)&Ahw[(mq*4+1)*AS + 2*l] = (half2v){(_Float16)h0_, (_Float16)h1_}; \
    h0_ = fmaxf(fmaf(dv4.z, u10, v10), 0.0f); h1_ = fmaxf(fmaf(dv4.z, u11, v11), 0.0f); \
    *(half2v*)&Ahw[(mq*4+2)*AS + 2*l] = (half2v){(_Float16)h0_, (_Float16)h1_}; \
    h0_ = fmaxf(fmaf(dv4.w, u10, v10), 0.0f); h1_ = fmaxf(fmaf(dv4.w, u11, v11), 0.0f); \
    *(half2v*)&Ahw[(mq*4+3)*AS + 2*l] = (half2v){(_Float16)h0_, (_Float16)h1_}; \
  } \
  wsync(); \
  half8 Ahi0 = *(const half8*)&Ahw[l15*AS +   0 + q4*8]; \
  half8 Ahi1 = *(const half8*)&Ahw[l15*AS +  32 + q4*8]; \
  half8 Ahi2 = *(const half8*)&Ahw[l15*AS +  64 + q4*8]; \
  half8 Ahi3 = *(const half8*)&Ahw[l15*AS +  96 + q4*8]; \
  wsync();   /* hi frag reads landed before lo overwrite (WAR) */ \
  _Pragma("unroll") \
  for (int mq=0;mq<4;mq++){ \
    float4 dv4 = ((const float4*)dp_)[mq]; \
    float h0_, h1_; _Float16 hh0_, hh1_; \
    h0_ = fmaxf(fmaf(dv4.x, u10, v10), 0.0f); h1_ = fmaxf(fmaf(dv4.x, u11, v11), 0.0f); \
    hh0_=(_Float16)h0_; hh1_=(_Float16)h1_; \
    *(half2v*)&Ahw[(mq*4+0)*AS + 2*l] = (half2v){(_Float16)(h0_-(float)hh0_), (_Float16)(h1_-(float)hh1_)}; \
    h0_ = fmaxf(fmaf(dv4.y, u10, v10), 0.0f); h1_ = fmaxf(fmaf(dv4.y, u11, v11), 0.0f); \
    hh0_=(_Float16)h0_; hh1_=(_Float16)h1_; \
    *(half2v*)&Ahw[(mq*4+1)*AS + 2*l] = (half2v){(_Float16)(h0_-(float)hh0_), (_Float16)(h1_-(float)hh1_)}; \
    h0_ = fmaxf(fmaf(dv4.z, u10, v10), 0.0f); h1_ = fmaxf(fmaf(dv4.z, u11, v11), 0.0f); \
    hh0_=(_Float16)h0_; hh1_=(_Float16)h1_; \
    *(half2v*)&Ahw[(mq*4+2)*AS + 2*l] = (half2v){(_Float16)(h0_-(float)hh0_), (_Float16)(h1_-(float)hh1_)}; \
    h0_ = fmaxf(fmaf(dv4.w, u10, v10), 0.0f); h1_ = fmaxf(fmaf(dv4.w, u11, v11), 0.0f); \
    hh0_=(_Float16)h0_; hh1_=(_Float16)h1_; \
    *(half2v*)&Ahw[(mq*4+3)*AS + 2*l] = (half2v){(_Float16)(h0_-(float)hh0_), (_Float16)(h1_-(float)hh1_)}; \
  } \
  wsync(); \
  floatx4 acc[8]; \
  _Pragma("unroll") \
  for (int i=0;i<8;i++) acc[i] = (floatx4){0.f,0.f,0.f,0.f}; \
  _Pragma("unroll") \
  for (int kt=0;kt<4;kt++){ \
    half8 Ahi_ = (kt==0)?Ahi0:(kt==1)?Ahi1:(kt==2)?Ahi2:Ahi3; \
    half8 Alo_ = *(const half8*)&Ahw[l15*AS + kt*32 + q4*8]; \
    _Pragma("unroll") \
    for (int i=0;i<8;i++){ \
      half8 B_ = *(const half8*)&W2f[((i*4+kt)*64 + l)*8]; \
      acc[i] = __builtin_amdgcn_mfma_f32_16x16x32_f16(Ahi_, B_, acc[i], 0,0,0); \
      acc[i] = __builtin_amdgcn_mfma_f32_16x16x32_f16(Alo_, B_, acc[i], 0,0,0); \
    } \
  } \
  float p0=0.f,p1=0.f,p2=0.f,p3=0.f; \
  _Pragma("unroll") \
  for (int i=0;i<8;i++){ \
    float bb = b2f[i*16+l15], ww = w3f[i*16+l15]; \
    p0 += fmaxf(acc[i][0]+bb,0.0f)*ww; \
    p1 += fmaxf(acc[i][1]+bb,0.0f)*ww; \
    p2 += fmaxf(acc[i][2]+bb,0.0f)*ww; \
    p3 += fmaxf(acc[i][3]+bb,0.0f)*ww; \
  } \
  _Pragma("unroll") \
  for (int off=1; off<16; off<<=1){ \
    p0 += __shfl_xor(p0, off, 64); \
    p1 += __shfl_xor(p1, off, 64); \
    p2 += __shfl_xor(p2, off, 64); \
    p3 += __shfl_xor(p3, off, 64); \
  } \
  if (l15==0){ \
    floatx4 o_ = {p0+b3v, p1+b3v, p2+b3v, p3+b3v}; \
    *((floatx4*)&(dstptr_)[q4*4]) = o_; \
  } \
  wsync(); \
} while(0)

__launch_bounds__(512, 4)
__global__ void neus_render_kernel(
    const float* __restrict__ rays_o, const float* __restrict__ rays_d,
    const float* __restrict__ W1, const float* __restrict__ b1,
    const float* __restrict__ W2, const float* __restrict__ b2,
    const float* __restrict__ W3, const float* __restrict__ b3,
    const float* __restrict__ R1, const float* __restrict__ r1,
    const float* __restrict__ R2, const float* __restrict__ r2,
    const float* __restrict__ s_val, float* __restrict__ out)
{
  // ---- shared: weights (block-shared) + per-ray scratch. Total = 80 KB exactly.
  __shared__ __align__(16) _Float16 W2f[2048*8];     // 32 KB
  __shared__ __align__(16) _Float16 R2f[256*8];      // 4 KB
  __shared__ __align__(16) _Float16 Ah[RPB][16*AS];  // 34 KB
  __shared__ __align__(16) float sDm[RPB][128];      // 4 KB
  __shared__ __align__(16) float sSm[RPB][128];      // 4 KB
  __shared__ __align__(16) float fDs[RPB][16];       // 512 B
  __shared__ __align__(16) float fSs[RPB][16];       // 512 B
  __shared__ float b2f[128], w3f[128];               // 1 KB

  const int t = threadIdx.x;

  // ---- cooperative weight staging
  #pragma unroll
  for (int r=0;r<4;r++){
    int row = t + r*512;
    int i = row>>8, kt=(row>>6)&3, lr=row&63;
    int q = lr>>4, n = i*16 + (lr&15);
    half8 v;
    #pragma unroll
    for (int j=0;j<8;j++) v[j] = (_Float16)W2[(kt*32+q*8+j)*128 + n];
    *(half8*)&W2f[row*8] = v;
  }
  if (t < 256){
    int kt=t>>6, lr=t&63, q=lr>>4, col=lr&15;
    half8 v;
    #pragma unroll
    for (int j=0;j<8;j++){
      int k = kt*32+q*8+j;
      v[j] = (col<3) ? (_Float16)R2[k*3+col] : (_Float16)0.0f;
    }
    *(half8*)&R2f[t*8] = v;
  }
  if (t < 128){ b2f[t]=b2[t]; w3f[t]=W3[t]; }
  __syncthreads();   // the only block-wide barrier

  const int wv = t>>6, l = t&63, l15 = t&15, q4 = (t>>4)&3;
  const int ray = blockIdx.x*RPB + wv;
  float b3v = b3[0];

  // ---- SDF layer-1 affine collapse ONLY (radiance uR/vR deferred to the
  //      radiance section — keeps the hot-loop live set minimal)
  float u10, v10, u11, v11;
  {
    float ro0 = rays_o[ray*3+0], ro1 = rays_o[ray*3+1], ro2 = rays_o[ray*3+2];
    float rx  = rays_d[ray*3+0], ry  = rays_d[ray*3+1], rz  = rays_d[ray*3+2];
    float nrm = sqrtf(rx*rx + ry*ry + rz*rz);
    float rd0 = rx/nrm, rd1 = ry/nrm, rd2 = rz/nrm;
    int k=2*l;
    float a=W1[k], b=W1[128+k], c=W1[256+k];
    u10 = rd0*a+rd1*b+rd2*c; v10 = ro0*a+ro1*b+ro2*c + b1[k];
    k=2*l+1;
    a=W1[k]; b=W1[128+k]; c=W1[256+k];
    u11 = rd0*a+rd1*b+rd2*c; v11 = ro0*a+ro1*b+ro2*c + b1[k];
  }

  _Float16* Ahw = &Ah[wv][0];
  float* sD = &sDm[wv][0];
  float* sS = &sSm[wv][0];

  // ---- initial d: linspace(0.5, 4.0, 64)
  {
    float tt = (float)l / 63.0f;
    sD[l] = 0.5f*(1.0f-tt) + 4.0f*tt;
  }
  wsync();
  for (int c=0;c<4;c++) EVAL16(&sD[c*16], &sS[c*16]);

  // ---- 4 upsampling iterations (wave-local; 2 samples/lane: t=l, t=64+l)
  for (int it=0; it<4; it++){
    const int n = 64 + 16*it;
    const int m = n-1;
    const float s_i = 64.0f * (float)(1<<it);

    float dc0 = sD[l],  sc0 = sS[l];
    float dn0 = sD[l+1], snn0 = sS[l+1];
    int lp0 = (l==0)?0:(l-1);
    float dp0 = sD[lp0], sp0 = sS[lp0];
    int i1 = 64+l;
    float dc1 = sD[i1 & 127], sc1 = sS[i1 & 127];
    int i1n = (i1+1) & 127;
    float dn1 = sD[i1n], snn1 = sS[i1n];
    float dp1 = sD[(i1-1) & 127], sp1 = sS[(i1-1) & 127];

    auto alpha_at = [&](float dp, float dc, float dn, float sp, float sc, float sn,
                        bool hasprev)->float{
      float mid = 0.5f*(sc+sn);
      float dv = (sn-sc)/(dn-dc+1e-5f);
      float pdv = hasprev ? (sc-sp)/(dc-dp+1e-5f) : 0.0f;
      float d2 = fminf(fminf(pdv,dv), 0.0f); d2 = fmaxf(d2,-10.0f);
      float dist = dn-dc;
      float pe = mid - d2*dist*0.5f, ne = mid + d2*dist*0.5f;
      float pc = sigm(pe*s_i), nc = sigm(ne*s_i);
      return (pc-nc+1e-5f)/(pc+1e-5f);
    };
    bool va0 = (l < m), va1 = (i1 < m);
    float a0 = va0 ? alpha_at(dp0,dc0,dn0,sp0,sc0,snn0, l>0)  : 0.0f;
    float a1 = va1 ? alpha_at(dp1,dc1,dn1,sp1,sc1,snn1, true) : 0.0f;

    float g0 = va0 ? (1.0f-a0+1e-10f) : 1.0f;
    float g1 = va1 ? (1.0f-a1+1e-10f) : 1.0f;
    #pragma unroll
    for (int off=1; off<64; off<<=1){ float y=__shfl_up(g0,off,64); if (l>=off) g0*=y; }
    float gtot0 = __shfl(g0, 63, 64);
    #pragma unroll
    for (int off=1; off<64; off<<=1){ float y=__shfl_up(g1,off,64); if (l>=off) g1*=y; }
    g1 *= gtot0;
    float T0 = __shfl_up(g0, 1, 64); if (l==0) T0 = 1.0f;
    float T1 = __shfl_up(g1, 1, 64); if (l==0) T1 = gtot0;

    float w0 = va0 ? (a0*T0 + 1e-5f) : 0.0f;
    float w1 = va1 ? (a1*T1 + 1e-5f) : 0.0f;
    #pragma unroll
    for (int off=1; off<64; off<<=1){ float y=__shfl_up(w0,off,64); if (l>=off) w0+=y; }
    float wtot0 = __shfl(w0, 63, 64);
    #pragma unroll
    for (int off=1; off<64; off<<=1){ float y=__shfl_up(w1,off,64); if (l>=off) w1+=y; }
    w1 += wtot0;
    float S = (m-1 < 64) ? __shfl(w0, m-1, 64) : __shfl(w1, m-65, 64);

    float csp0 = __shfl_up(w0, 1, 64);
    float cdf0 = (l==0) ? 0.0f : csp0/S;
    float csp1 = __shfl_up(w1, 1, 64);
    float c63  = __shfl(w0, 63, 64);
    float cdf1r = ((l==0) ? c63 : csp1)/S;
    float cdf1m = (i1 < n) ? cdf1r : 2.0f;

    int ind = 0;
    #pragma unroll
    for (int q=0;q<16;q++){
      float u = (float)q/15.0f;
      unsigned long long bq0 = __ballot(cdf0 <= u);
      unsigned long long bq1 = __ballot(cdf1m <= u);
      int c = __popcll(bq0) + __popcll(bq1);
      if (l==q) ind = c;
    }
    {
      float u = (float)l15/15.0f;
      int below = ind-1; if (below<0) below=0; if (below>n-1) below=n-1;
      int above = ind;   if (above>n-1) above=n-1;
      float cb = (below<64) ? __shfl(cdf0, below, 64) : __shfl(cdf1r, below-64, 64);
      float ca = (above<64) ? __shfl(cdf0, above, 64) : __shfl(cdf1r, above-64, 64);
      float bb = sD[below], ba = sD[above];
      float den = ca - cb; if (den < 1e-5f) den = 1.0f;
      float tt = (u - cb)/den;
      float fdnew = bb + tt*(ba-bb);
      if (l < 16) fDs[wv][l] = fdnew;
    }
    wsync();

    EVAL16(&fDs[wv][0], &fSs[wv][0]);

    // stable merge
    {
      const float4* fp4 = (const float4*)&fDs[wv][0];
      float4 fa = fp4[0], fb = fp4[1], fc = fp4[2], fd = fp4[3];
      float fq[16] = {fa.x,fa.y,fa.z,fa.w, fb.x,fb.y,fb.z,fb.w,
                      fc.x,fc.y,fc.z,fc.w, fd.x,fd.y,fd.z,fd.w};
      float fdv = fDs[wv][l15];
      float fsv = fSs[wv][l15];
      bool v1 = (i1 < n);
      int rold0 = l, rold1 = i1;
      #pragma unroll
      for (int q=0;q<16;q++){
        rold0 += (fq[q] < dc0) ? 1 : 0;
        rold1 += (fq[q] < dc1) ? 1 : 0;
      }
      int rf = 0;
      #pragma unroll
      for (int q=0;q<16;q++){
        unsigned long long bq0 = __ballot(dc0 <= fq[q]);
        unsigned long long bq1 = __ballot(v1 && (dc1 <= fq[q]));
        int c = q + __popcll(bq0) + __popcll(bq1);
        if (l==q) rf = c;
      }
      wsync();
      sD[rold0] = dc0; sS[rold0] = sc0;
      if (v1){ sD[rold1] = dc1; sS[rold1] = sc1; }
      if (l < 16){ sD[rf] = fdv; sS[rf] = fsv; }
      wsync();
    }
  }

  // ---- final compositing (sdf_final == carried sS; n = 128)
  float dm0, dm1, vw0, vw1;
  {
    float sfin = s_val[0] * 64.0f;     // recomputed here (not carried)
    float d0 = sD[l],  d1 = sD[64+l];
    float s0 = sS[l],  s1 = sS[64+l];
    float dn0 = sD[l+1], sn0 = sS[l+1];
    int i1n = (65+l) & 127;
    float dn1 = sD[i1n], sn1 = sS[i1n];
    bool v1a = (l < 63);
    float cf0 = sigm(s0*sfin), cfn0 = sigm(sn0*sfin);
    float a0 = (cf0-cfn0+1e-5f)/(cf0+1e-5f);
    a0 = fminf(fmaxf(a0,0.0f),1.0f);
    float cf1 = sigm(s1*sfin), cfn1 = sigm(sn1*sfin);
    float a1 = (cf1-cfn1+1e-5f)/(cf1+1e-5f);
    a1 = v1a ? fminf(fmaxf(a1,0.0f),1.0f) : 0.0f;
    dm0 = 0.5f*(d0+dn0);
    dm1 = v1a ? 0.5f*(d1+dn1) : 0.0f;

    float g0 = 1.0f-a0+1e-10f;
    float g1 = v1a ? (1.0f-a1+1e-10f) : 1.0f;
    #pragma unroll
    for (int off=1; off<64; off<<=1){ float y=__shfl_up(g0,off,64); if (l>=off) g0*=y; }
    float gtot0 = __shfl(g0, 63, 64);
    #pragma unroll
    for (int off=1; off<64; off<<=1){ float y=__shfl_up(g1,off,64); if (l>=off) g1*=y; }
    g1 *= gtot0;
    float T0 = __shfl_up(g0, 1, 64); if (l==0) T0 = 1.0f;
    float T1 = __shfl_up(g1, 1, 64); if (l==0) T1 = gtot0;
    vw0 = a0*T0;
    vw1 = a1*T1;
    wsync();
    sD[l] = dm0; sD[64+l] = dm1;               // sD := d_mid, sS := vis_w
    sS[l] = vw0; sS[64+l] = vw1;
    wsync();
  }

  // ---- radiance net: re-derive ray data + affine collapse HERE (deferred)
  float uR0, vR0, uR1, vR1, r2lane;
  {
    float ro0 = rays_o[ray*3+0], ro1 = rays_o[ray*3+1], ro2 = rays_o[ray*3+2];
    float rx  = rays_d[ray*3+0], ry  = rays_d[ray*3+1], rz  = rays_d[ray*3+2];
    float nrm = sqrtf(rx*rx + ry*ry + rz*rz);
    float rd0 = rx/nrm, rd1 = ry/nrm, rd2 = rz/nrm;
    int k=2*l;
    float p=R1[k], qq=R1[128+k], s=R1[256+k], d=R1[384+k], e=R1[512+k], f=R1[640+k];
    uR0 = rd0*p+rd1*qq+rd2*s;
    vR0 = ro0*p+ro1*qq+ro2*s + rd0*d+rd1*e+rd2*f + r1[k];
    k=2*l+1;
    p=R1[k]; qq=R1[128+k]; s=R1[256+k]; d=R1[384+k]; e=R1[512+k]; f=R1[640+k];
    uR1 = rd0*p+rd1*qq+rd2*s;
    vR1 = ro0*p+ro1*qq+ro2*s + rd0*d+rd1*e+rd2*f + r1[k];
    r2lane = (l15==0) ? r2[0] : (l15==1) ? r2[1] : (l15==2) ? r2[2] : 0.0f;
  }

  half8 RB[4];
  #pragma unroll
  for (int kt=0;kt<4;kt++) RB[kt] = *(const half8*)&R2f[(kt*64+l)*8];
  float rgb = 0.0f;
  for (int g=0; g<8; g++){
    #pragma unroll
    for (int mq=0;mq<4;mq++){
      float4 dv4 = ((const float4*)&sDm[wv][g*16])[mq];
      float h0, h1;
      h0 = fmaxf(fmaf(dv4.x, uR0, vR0), 0.0f); h1 = fmaxf(fmaf(dv4.x, uR1, vR1), 0.0f);
      *(half2v*)&Ahw[(mq*4+0)*AS + 2*l] = (half2v){(_Float16)h0, (_Float16)h1};
      h0 = fmaxf(fmaf(dv4.y, uR0, vR0), 0.0f); h1 = fmaxf(fmaf(dv4.y, uR1, vR1), 0.0f);
      *(half2v*)&Ahw[(mq*4+1)*AS + 2*l] = (half2v){(_Float16)h0, (_Float16)h1};
      h0 = fmaxf(fmaf(dv4.z, uR0, vR0), 0.0f); h1 = fmaxf(fmaf(dv4.z, uR1, vR1), 0.0f);
      *(half2v*)&Ahw[(mq*4+2)*AS + 2*l] = (half2v){(_Float16)h0, (_Float16)h1};
      h0 = fmaxf(fmaf(dv4.w, uR0, vR0), 0.0f); h1 = fmaxf(fmaf(dv4.w, uR1, vR1), 0.0f);
      *(half2v*)&Ahw[(mq*4+3)*AS + 2*l] = (half2v){(_Float16)h0, (_Float16)h1};
    }
    wsync();
    half8 A[4];
    #pragma unroll
    for (int kt=0;kt<4;kt++)
      A[kt] = *(const half8*)&Ahw[l15*AS + kt*32 + q4*8];
    floatx4 racc = (floatx4){0.f,0.f,0.f,0.f};
    #pragma unroll
    for (int kt=0;kt<4;kt++)
      racc = __builtin_amdgcn_mfma_f32_16x16x32_f16(A[kt], RB[kt], racc, 0,0,0);
    #pragma unroll
    for (int r=0;r<4;r++){
      int pt = g*16 + q4*4 + r;
      float w = sS[pt];
      rgb += w * sigm(racc[r] + r2lane);
    }
    wsync();
  }

  // ---- reductions + output
  float v3 = dm0*vw0 + dm1*vw1;
  float v4 = vw0 + vw1;
  #pragma unroll
  for (int off=32; off>=1; off>>=1){
    v3 += __shfl_xor(v3, off, 64);
    v4 += __shfl_xor(v4, off, 64);
  }
  rgb += __shfl_xor(rgb, 16, 64);
  rgb += __shfl_xor(rgb, 32, 64);
  if (l < 3)  out[ray*5 + l] = rgb;
  if (l == 3) out[ray*5 + 3] = v3;
  if (l == 4) out[ray*5 + 4] = v4;
}

extern "C" void kernel_launch(void* const* d_in, const int* in_sizes, int n_in,
                              void* d_out, int out_size, void* d_ws, size_t ws_size,
                              hipStream_t stream) {
  const float* rays_o = (const float*)d_in[0];
  const float* rays_d = (const float*)d_in[1];
  const float* W1 = (const float*)d_in[2];
  const float* b1 = (const float*)d_in[3];
  const float* W2 = (const float*)d_in[4];
  const float* b2 = (const float*)d_in[5];
  const float* W3 = (const float*)d_in[6];
  const float* b3 = (const float*)d_in[7];
  const float* R1 = (const float*)d_in[8];
  const float* r1 = (const float*)d_in[9];
  const float* R2 = (const float*)d_in[10];
  const float* r2 = (const float*)d_in[11];
  const float* sv = (const float*)d_in[12];
  float* out = (float*)d_out;
  neus_render_kernel<<<NRAYS/RPB, 512, 0, stream>>>(
      rays_o, rays_d, W1, b1, W2, b2, W3, b3, R1, r1, R2, r2, sv, out);
}